// Round 11
// baseline (277.484 us; speedup 1.0000x reference)
//
#include <hip/hip_runtime.h>
#include <hip/hip_bf16.h>
#include <cstdint>

#define B_   2
#define N_   1024
#define DN_  128
#define DE_  16
#define DG_  128
#define MID_ 64
#define OUT_ 128
#define TI_  2
#define PR_ROWS 4

typedef short bf16x8 __attribute__((ext_vector_type(8)));
typedef float f32x4  __attribute__((ext_vector_type(4)));

__device__ inline short f2bf(float f) {
    union { float f; unsigned u; } v; v.f = f;
    unsigned r = v.u + 0x7FFFu + ((v.u >> 16) & 1u);   // RTNE
    return (short)(unsigned short)(r >> 16);
}

__device__ inline unsigned pk2(float lo, float hi) {
    union { __hip_bfloat162 h; unsigned u; } p;
    p.h = __float22bfloat162_rn(make_float2(lo, hi));  // v_cvt_pk_bf16_f32
    return p.u;
}

// ---------------------------------------------------------------------------
// Fused prep kernel (R10 version — 8-wide load batching, kept).
// ---------------------------------------------------------------------------
__global__ void __launch_bounds__(384) prep_all(
    const float* __restrict__ features, const float* __restrict__ g_features,
    const float* __restrict__ Wm, const float* __restrict__ bm,
    const float* __restrict__ Wskip, const float* __restrict__ bskip,
    const float* __restrict__ W1, const float* __restrict__ b1,
    const float* __restrict__ W2, const float* __restrict__ b2,
    const float* __restrict__ We, const float* __restrict__ be,
    const float* __restrict__ Wg, const float* __restrict__ bg,
    float* __restrict__ values, float* __restrict__ skipo,
    float* __restrict__ P1x, float* __restrict__ p2,
    float* __restrict__ pg, short* __restrict__ We_frag)
{
    const int t   = threadIdx.x;
    const int blk = blockIdx.x;

    if (blk == 512) {                       // --- We fragment prep ---
        for (int e = t; e < 4 * 64 * 8; e += 384) {
            const int c    = e >> 9;
            const int lane = (e >> 3) & 63;
            const int j    = e & 7;
            const int quad = lane >> 4, s = lane & 15;
            short v = 0;
            if (quad < 2) v = f2bf(We[(quad * 8 + j) * MID_ + c * 16 + s]);
            We_frag[e] = v;
        }
        return;
    }
    if (blk == 513) {                       // --- pg ---
        if (t < MID_) {
            float a0 = bg[t], a1 = bg[t];
            for (int k0 = 0; k0 < DG_; k0 += 8) {
                float w[8];
                #pragma unroll
                for (int u = 0; u < 8; ++u) w[u] = Wg[(k0 + u) * MID_ + t];
                #pragma unroll
                for (int u = 0; u < 8; ++u) {
                    a0 += g_features[k0 + u] * w[u];
                    a1 += g_features[DG_ + k0 + u] * w[u];
                }
            }
            pg[t] = a0; pg[MID_ + t] = a1;
        }
        return;
    }

    // --- per-node projections ---
    const int r0 = blk * PR_ROWS;
    __shared__ float feat[PR_ROWS][DN_];
    for (int idx = t; idx < PR_ROWS * DN_; idx += 384)
        feat[idx >> 7][idx & 127] = features[(size_t)r0 * DN_ + idx];
    __syncthreads();

    const float* W; int c, stride; float base; float* outp; int ostride;
    if (t < 128) {
        W = Wm;    c = t;       stride = OUT_; base = bm[c];
        outp = values + (size_t)r0 * OUT_ + c; ostride = OUT_;
    } else if (t < 256) {
        W = Wskip; c = t - 128; stride = OUT_; base = bskip[c];
        outp = skipo + (size_t)r0 * OUT_ + c;  ostride = OUT_;
    } else if (t < 320) {
        W = W1;    c = t - 256; stride = MID_; base = b1[c] + be[c];
        outp = P1x + (size_t)r0 * MID_ + c;    ostride = MID_;
    } else {
        W = W2;    c = t - 320; stride = MID_; base = b2[c];
        outp = p2 + (size_t)r0 * MID_ + c;     ostride = MID_;
    }

    float acc[PR_ROWS] = {};
    for (int k0 = 0; k0 < DN_; k0 += 8) {
        float w[8];
        #pragma unroll
        for (int u = 0; u < 8; ++u) w[u] = W[(k0 + u) * stride + c];
        #pragma unroll
        for (int u = 0; u < 8; ++u)
            #pragma unroll
            for (int q = 0; q < PR_ROWS; ++q) acc[q] += feat[q][k0 + u] * w[u];
    }
    #pragma unroll
    for (int q = 0; q < PR_ROWS; ++q) outp[q * ostride] = acc[q] + base;
}

// ---------------------------------------------------------------------------
// Main fused kernel (R11): R10 structure + deeper latency cover.
// R10 post-mortem: VALUBusy ~42% at full 16-wave/CU residency = exposed VMEM
// latency in-loop. Little's law: 2.2KB in flight/CU vs ~9KB needed.
//  - e-prefetch depth 3 (eA[3], it%3 static under full unroll): issue->use
//    ~1200cy > ~900cy HBM latency (depth 2 was ~800cy, marginally short).
//  - Pass C: #pragma unroll 4 -> compiler batches 4 iterations' L2 loads
//    ahead of the FMA block.
// ---------------------------------------------------------------------------
__global__ void __launch_bounds__(256) gat_main(
    const float* __restrict__ e_features, const float* __restrict__ adj,
    const short* __restrict__ We_frag, const float* __restrict__ Wa,
    const float* __restrict__ values, const float* __restrict__ skipo,
    const float* __restrict__ P1x, const float* __restrict__ p2,
    const float* __restrict__ pg, float* __restrict__ out)
{
    const int t    = threadIdx.x;
    const int wv   = t >> 6;                          // 0..3
    const int l    = t & 63;
    const int quad = l >> 4;
    const int s    = l & 15;
    const int r    = blockIdx.x;
    const int b    = (r >> 2) & 1;                    // XCD r%8 -> one batch
    const int i0   = (((r >> 3) << 2) | (r & 3)) * TI_;

    __shared__ float lgP[TI_][N_];
    __shared__ float redv[4][16][20];
    __shared__ float sinv[TI_];
    __shared__ float pmax[4];
    __shared__ float psum[4];

    // ---- block constants ----
    bf16x8 bfr[4];                                    // We A-fragments
    float4 wa4[4];                                    // Wa for this lane's mids
    f32x4  p2l[TI_][4];                               // p2+pg as MFMA C-operand
    #pragma unroll
    for (int c = 0; c < 4; ++c) {
        bfr[c] = *(const bf16x8*)&We_frag[(c * 64 + l) * 8];
        wa4[c] = *(const float4*)&Wa[c * 16 + quad * 4];
        const float4 pg4 = *(const float4*)&pg[b * MID_ + c * 16 + quad * 4];
        #pragma unroll
        for (int ii = 0; ii < TI_; ++ii) {
            const float4 p4 = *(const float4*)&p2[((size_t)(b * N_ + i0 + ii)) * MID_ + c * 16 + quad * 4];
            p2l[ii][c][0] = p4.x + pg4.x;
            p2l[ii][c][1] = p4.y + pg4.y;
            p2l[ii][c][2] = p4.z + pg4.z;
            p2l[ii][c][3] = p4.w + pg4.w;
        }
    }
    const size_t erow0 = (size_t)(b * N_ + i0) * N_;

    float4 eA[3][TI_][2];                             // 3-deep e rotation
    float  bb[2][4][4];                               // bias ping-pong

    auto loadE = [&](int buf, int tile) {
        if (quad < 2) {
            #pragma unroll
            for (int ii = 0; ii < TI_; ++ii) {
                const float* ep = &e_features[(erow0 + (size_t)ii * N_ + (size_t)tile * 16 + s) * DE_ + quad * 8];
                eA[buf][ii][0] = *(const float4*)ep;
                eA[buf][ii][1] = *(const float4*)(ep + 4);
            }
        }
    };
    auto loadB = [&](int buf, int tile) {
        const float* pb = &P1x[(size_t)(b * N_ + tile * 16 + s) * MID_ + quad * 4];
        #pragma unroll
        for (int c = 0; c < 4; ++c) {
            const float4 v = *(const float4*)(pb + c * 16);
            bb[buf][c][0] = v.x; bb[buf][c][1] = v.y;
            bb[buf][c][2] = v.z; bb[buf][c][3] = v.w;
        }
    };

    // ---- Pass A prologue: 3 e-tiles + 1 bias tile in flight ----
    loadE(0, wv);
    loadE(1, wv + 4);
    loadE(2, wv + 8);
    loadB(0, wv);

    #pragma unroll
    for (int it = 0; it < 16; ++it) {                 // full unroll: static idx
        const int tile = wv + it * 4;
        const int j0   = tile * 16;

        // pack current e -> B fragments
        unsigned af[TI_][4];
        #pragma unroll
        for (int ii = 0; ii < TI_; ++ii) {
            if (quad < 2) {
                af[ii][0] = pk2(eA[it % 3][ii][0].x, eA[it % 3][ii][0].y);
                af[ii][1] = pk2(eA[it % 3][ii][0].z, eA[it % 3][ii][0].w);
                af[ii][2] = pk2(eA[it % 3][ii][1].x, eA[it % 3][ii][1].y);
                af[ii][3] = pk2(eA[it % 3][ii][1].z, eA[it % 3][ii][1].w);
            } else {
                af[ii][0] = af[ii][1] = af[ii][2] = af[ii][3] = 0u;
            }
        }
        // refill this e-buffer for tile it+3
        if (it < 13) loadE(it % 3, tile + 12);
        // prefetch next tile's bias (consumed post-MFMA next iteration)
        if (it < 15) loadB((it + 1) & 1, tile + 4);

        #pragma unroll
        for (int ii = 0; ii < TI_; ++ii) {
            union { unsigned u[4]; bf16x8 v; } a;
            a.u[0] = af[ii][0]; a.u[1] = af[ii][1];
            a.u[2] = af[ii][2]; a.u[3] = af[ii][3];
            f32x4 acc[4];
            #pragma unroll
            for (int c = 0; c < 4; ++c)
                acc[c] = __builtin_amdgcn_mfma_f32_16x16x32_bf16(bfr[c], a.v, p2l[ii][c], 0, 0, 0);
            // epilogue: leaky-relu + dot(Wa) as a reduction tree (dep ~5)
            float tc[4];
            #pragma unroll
            for (int c = 0; c < 4; ++c) {
                const float w0 = (c == 0 ? wa4[0].x : c == 1 ? wa4[1].x : c == 2 ? wa4[2].x : wa4[3].x);
                const float w1 = (c == 0 ? wa4[0].y : c == 1 ? wa4[1].y : c == 2 ? wa4[2].y : wa4[3].y);
                const float w2 = (c == 0 ? wa4[0].z : c == 1 ? wa4[1].z : c == 2 ? wa4[2].z : wa4[3].z);
                const float w3 = (c == 0 ? wa4[0].w : c == 1 ? wa4[1].w : c == 2 ? wa4[2].w : wa4[3].w);
                float x0 = acc[c][0] + bb[it & 1][c][0];
                float x1 = acc[c][1] + bb[it & 1][c][1];
                float x2 = acc[c][2] + bb[it & 1][c][2];
                float x3 = acc[c][3] + bb[it & 1][c][3];
                x0 = fmaxf(x0, 0.01f * x0);
                x1 = fmaxf(x1, 0.01f * x1);
                x2 = fmaxf(x2, 0.01f * x2);
                x3 = fmaxf(x3, 0.01f * x3);
                tc[c] = (x0 * w0 + x1 * w1) + (x2 * w2 + x3 * w3);
            }
            float part = (tc[0] + tc[1]) + (tc[2] + tc[3]);
            part += __shfl_xor(part, 16);
            part += __shfl_xor(part, 32);
            if (l < 16) lgP[ii][j0 + l] = part;
        }
    }
    __syncthreads();

    // ---- Pass B: masked softmax, wave wv owns row (wv&1), half (wv>>1) ----
    {
        const int rw = wv & 1, h = wv >> 1;
        const int c0 = h * 512 + l * 4;
        const size_t arb = (size_t)(b * N_ + i0 + rw) * N_;
        float4 lv[2], av[2];
        #pragma unroll
        for (int q = 0; q < 2; ++q) {
            lv[q] = *(const float4*)&lgP[rw][c0 + 256 * q];
            av[q] = *(const float4*)&adj[arb + c0 + 256 * q];
        }
        const float NEG = -3.4e38f;
        float m = NEG;
        #pragma unroll
        for (int q = 0; q < 2; ++q) {
            m = fmaxf(m, av[q].x > 0.f ? lv[q].x : NEG);
            m = fmaxf(m, av[q].y > 0.f ? lv[q].y : NEG);
            m = fmaxf(m, av[q].z > 0.f ? lv[q].z : NEG);
            m = fmaxf(m, av[q].w > 0.f ? lv[q].w : NEG);
        }
        #pragma unroll
        for (int o = 1; o < 64; o <<= 1) m = fmaxf(m, __shfl_xor(m, o));
        if (l == 0) pmax[wv] = m;
        __syncthreads();
        m = fmaxf(pmax[rw], pmax[2 + rw]);
        float sum = 0.f;
        #pragma unroll
        for (int q = 0; q < 2; ++q) {
            float4 e4;
            e4.x = av[q].x > 0.f ? __expf(lv[q].x - m) : 0.f;
            e4.y = av[q].y > 0.f ? __expf(lv[q].y - m) : 0.f;
            e4.z = av[q].z > 0.f ? __expf(lv[q].z - m) : 0.f;
            e4.w = av[q].w > 0.f ? __expf(lv[q].w - m) : 0.f;
            *(float4*)&lgP[rw][c0 + 256 * q] = e4;
            sum += (e4.x + e4.y) + (e4.z + e4.w);
        }
        #pragma unroll
        for (int o = 1; o < 64; o <<= 1) sum += __shfl_xor(sum, o);
        if (l == 0) psum[wv] = sum;
        __syncthreads();
        if (t < TI_) sinv[t] = 1.0f / (psum[t] + psum[t + 2]);
        // lgP exp-writes are pre-psum-barrier; sinv read after redv barrier.
    }

    // ---- Pass C: (exp @ values) shared across the 2 i-rows ----
    const int cg = l & 15, jp = l >> 4, ch0 = cg * 8;
    float acc[TI_][8] = {};
    const float* vb = values + (size_t)b * N_ * OUT_ + ch0;
    #pragma unroll 4
    for (int k = 0; k < 64; ++k) {
        const int j = wv * 4 + jp + k * 16;
        float cw[TI_];
        #pragma unroll
        for (int ii = 0; ii < TI_; ++ii) cw[ii] = lgP[ii][j];
        const float* vp = vb + (size_t)j * OUT_;
        const float4 v0 = *(const float4*)vp;
        const float4 v1 = *(const float4*)(vp + 4);
        const float vv[8] = {v0.x, v0.y, v0.z, v0.w, v1.x, v1.y, v1.z, v1.w};
        #pragma unroll
        for (int ii = 0; ii < TI_; ++ii)
            #pragma unroll
            for (int kk = 0; kk < 8; ++kk)
                acc[ii][kk] += cw[ii] * vv[kk];
    }
    #pragma unroll
    for (int ii = 0; ii < TI_; ++ii)
        #pragma unroll
        for (int kk = 0; kk < 8; ++kk) {
            acc[ii][kk] += __shfl_xor(acc[ii][kk], 16);
            acc[ii][kk] += __shfl_xor(acc[ii][kk], 32);
        }
    if (l < 16) {
        #pragma unroll
        for (int ii = 0; ii < TI_; ++ii)
            #pragma unroll
            for (int q = 0; q < 2; ++q) {
                float4 w4 = make_float4(acc[ii][q * 4], acc[ii][q * 4 + 1],
                                        acc[ii][q * 4 + 2], acc[ii][q * 4 + 3]);
                *(float4*)&redv[wv][l][ii * 8 + q * 4] = w4;
            }
    }
    __syncthreads();
    {
        const int ch = t & 127, g = ch >> 3, kk = ch & 7;
        const int ii = t >> 7;                        // 0..1
        float sum = redv[0][g][ii * 8 + kk];
        #pragma unroll
        for (int w = 1; w < 4; ++w) sum += redv[w][g][ii * 8 + kk];
        const size_t ob = ((size_t)(b * N_ + i0 + ii)) * OUT_ + ch;
        out[ob] = fmaxf(sum * sinv[ii] + skipo[ob], 0.f);
    }
}

extern "C" void kernel_launch(void* const* d_in, const int* in_sizes, int n_in,
                              void* d_out, int out_size, void* d_ws, size_t ws_size,
                              hipStream_t stream) {
    const float* features   = (const float*)d_in[0];
    const float* e_features = (const float*)d_in[1];
    const float* g_features = (const float*)d_in[2];
    const float* adj        = (const float*)d_in[3];
    const float* Wm    = (const float*)d_in[4];
    const float* bm    = (const float*)d_in[5];
    const float* Wskip = (const float*)d_in[6];
    const float* bskip = (const float*)d_in[7];
    const float* W1    = (const float*)d_in[8];
    const float* b1    = (const float*)d_in[9];
    const float* W2    = (const float*)d_in[10];
    const float* b2    = (const float*)d_in[11];
    const float* We    = (const float*)d_in[12];
    const float* be    = (const float*)d_in[13];
    const float* Wg    = (const float*)d_in[14];
    const float* bg    = (const float*)d_in[15];
    const float* Wa    = (const float*)d_in[16];
    float* out = (float*)d_out;

    float* ws      = (float*)d_ws;
    float* values  = ws;                    // 262144 floats
    float* skipo   = ws + 262144;           // 262144
    float* P1x     = ws + 524288;           // 131072 (row-major [node][mid])
    float* p2      = ws + 655360;           // 131072
    float* pg      = ws + 786432;           // 128
    short* We_frag = (short*)(ws + 786560); // 2048 shorts (1024 floats)

    prep_all<<<B_ * N_ / PR_ROWS + 2, 384, 0, stream>>>(
        features, g_features, Wm, bm, Wskip, bskip, W1, b1, W2, b2,
        We, be, Wg, bg, values, skipo, P1x, p2, pg, We_frag);
    gat_main<<<B_ * N_ / TI_, 256, 0, stream>>>(
        e_features, adj, We_frag, Wa, values, skipo, P1x, p2, pg, out);
}

// Round 12
// 274.304 us; speedup vs baseline: 1.0116x; 1.0116x over previous
//
#include <hip/hip_runtime.h>
#include <hip/hip_bf16.h>
#include <cstdint>

#define B_   2
#define N_   1024
#define DN_  128
#define DE_  16
#define DG_  128
#define MID_ 64
#define OUT_ 128
#define TI_  2
#define PR_ROWS 4

typedef short bf16x8 __attribute__((ext_vector_type(8)));
typedef float f32x4  __attribute__((ext_vector_type(4)));

__device__ inline short f2bf(float f) {
    union { float f; unsigned u; } v; v.f = f;
    unsigned r = v.u + 0x7FFFu + ((v.u >> 16) & 1u);   // RTNE
    return (short)(unsigned short)(r >> 16);
}

__device__ inline unsigned pk2(float lo, float hi) {
    union { __hip_bfloat162 h; unsigned u; } p;
    p.h = __float22bfloat162_rn(make_float2(lo, hi));  // v_cvt_pk_bf16_f32
    return p.u;
}

// ---------------------------------------------------------------------------
// Fused prep kernel (R10 version — 8-wide load batching, kept).
// ---------------------------------------------------------------------------
__global__ void __launch_bounds__(384) prep_all(
    const float* __restrict__ features, const float* __restrict__ g_features,
    const float* __restrict__ Wm, const float* __restrict__ bm,
    const float* __restrict__ Wskip, const float* __restrict__ bskip,
    const float* __restrict__ W1, const float* __restrict__ b1,
    const float* __restrict__ W2, const float* __restrict__ b2,
    const float* __restrict__ We, const float* __restrict__ be,
    const float* __restrict__ Wg, const float* __restrict__ bg,
    float* __restrict__ values, float* __restrict__ skipo,
    float* __restrict__ P1x, float* __restrict__ p2,
    float* __restrict__ pg, short* __restrict__ We_frag)
{
    const int t   = threadIdx.x;
    const int blk = blockIdx.x;

    if (blk == 512) {                       // --- We fragment prep ---
        for (int e = t; e < 4 * 64 * 8; e += 384) {
            const int c    = e >> 9;
            const int lane = (e >> 3) & 63;
            const int j    = e & 7;
            const int quad = lane >> 4, s = lane & 15;
            short v = 0;
            if (quad < 2) v = f2bf(We[(quad * 8 + j) * MID_ + c * 16 + s]);
            We_frag[e] = v;
        }
        return;
    }
    if (blk == 513) {                       // --- pg ---
        if (t < MID_) {
            float a0 = bg[t], a1 = bg[t];
            for (int k0 = 0; k0 < DG_; k0 += 8) {
                float w[8];
                #pragma unroll
                for (int u = 0; u < 8; ++u) w[u] = Wg[(k0 + u) * MID_ + t];
                #pragma unroll
                for (int u = 0; u < 8; ++u) {
                    a0 += g_features[k0 + u] * w[u];
                    a1 += g_features[DG_ + k0 + u] * w[u];
                }
            }
            pg[t] = a0; pg[MID_ + t] = a1;
        }
        return;
    }

    // --- per-node projections ---
    const int r0 = blk * PR_ROWS;
    __shared__ float feat[PR_ROWS][DN_];
    for (int idx = t; idx < PR_ROWS * DN_; idx += 384)
        feat[idx >> 7][idx & 127] = features[(size_t)r0 * DN_ + idx];
    __syncthreads();

    const float* W; int c, stride; float base; float* outp; int ostride;
    if (t < 128) {
        W = Wm;    c = t;       stride = OUT_; base = bm[c];
        outp = values + (size_t)r0 * OUT_ + c; ostride = OUT_;
    } else if (t < 256) {
        W = Wskip; c = t - 128; stride = OUT_; base = bskip[c];
        outp = skipo + (size_t)r0 * OUT_ + c;  ostride = OUT_;
    } else if (t < 320) {
        W = W1;    c = t - 256; stride = MID_; base = b1[c] + be[c];
        outp = P1x + (size_t)r0 * MID_ + c;    ostride = MID_;
    } else {
        W = W2;    c = t - 320; stride = MID_; base = b2[c];
        outp = p2 + (size_t)r0 * MID_ + c;     ostride = MID_;
    }

    float acc[PR_ROWS] = {};
    for (int k0 = 0; k0 < DN_; k0 += 8) {
        float w[8];
        #pragma unroll
        for (int u = 0; u < 8; ++u) w[u] = W[(k0 + u) * stride + c];
        #pragma unroll
        for (int u = 0; u < 8; ++u)
            #pragma unroll
            for (int q = 0; q < PR_ROWS; ++q) acc[q] += feat[q][k0 + u] * w[u];
    }
    #pragma unroll
    for (int q = 0; q < PR_ROWS; ++q) outp[q * ostride] = acc[q] + base;
}

// ---------------------------------------------------------------------------
// Main fused kernel (R12): R10 structure + bias prefetch distance-2.
// R11 post-mortem: profiled 150us was clock throttle (timed run identical);
// e-depth-3 + unroll-4 were NEUTRAL -> e-stream is covered; reverted.
// Remaining exposed latency: bb (P1x bias) was prefetched distance-1
// (~350cy cover vs 200-600cy L2/L3) and feeds the epilogue right after the
// MFMA on every iteration. Fix: bb[3] rotation, loaded 2 tiles ahead
// (it%3 static under full unroll). +16 VGPR -> ~124, stays under the 128
// occupancy cliff.
// ---------------------------------------------------------------------------
__global__ void __launch_bounds__(256) gat_main(
    const float* __restrict__ e_features, const float* __restrict__ adj,
    const short* __restrict__ We_frag, const float* __restrict__ Wa,
    const float* __restrict__ values, const float* __restrict__ skipo,
    const float* __restrict__ P1x, const float* __restrict__ p2,
    const float* __restrict__ pg, float* __restrict__ out)
{
    const int t    = threadIdx.x;
    const int wv   = t >> 6;                          // 0..3
    const int l    = t & 63;
    const int quad = l >> 4;
    const int s    = l & 15;
    const int r    = blockIdx.x;
    const int b    = (r >> 2) & 1;                    // XCD r%8 -> one batch
    const int i0   = (((r >> 3) << 2) | (r & 3)) * TI_;

    __shared__ float lgP[TI_][N_];
    __shared__ float redv[4][16][20];
    __shared__ float sinv[TI_];
    __shared__ float pmax[4];
    __shared__ float psum[4];

    // ---- block constants ----
    bf16x8 bfr[4];                                    // We A-fragments
    float4 wa4[4];                                    // Wa for this lane's mids
    f32x4  p2l[TI_][4];                               // p2+pg as MFMA C-operand
    #pragma unroll
    for (int c = 0; c < 4; ++c) {
        bfr[c] = *(const bf16x8*)&We_frag[(c * 64 + l) * 8];
        wa4[c] = *(const float4*)&Wa[c * 16 + quad * 4];
        const float4 pg4 = *(const float4*)&pg[b * MID_ + c * 16 + quad * 4];
        #pragma unroll
        for (int ii = 0; ii < TI_; ++ii) {
            const float4 p4 = *(const float4*)&p2[((size_t)(b * N_ + i0 + ii)) * MID_ + c * 16 + quad * 4];
            p2l[ii][c][0] = p4.x + pg4.x;
            p2l[ii][c][1] = p4.y + pg4.y;
            p2l[ii][c][2] = p4.z + pg4.z;
            p2l[ii][c][3] = p4.w + pg4.w;
        }
    }
    const size_t erow0 = (size_t)(b * N_ + i0) * N_;

    float4 eA[2][TI_][2];                             // 2-deep e rotation
    float  bb[3][4][4];                               // bias, distance-2 rotation

    auto loadE = [&](int buf, int tile) {
        if (quad < 2) {
            #pragma unroll
            for (int ii = 0; ii < TI_; ++ii) {
                const float* ep = &e_features[(erow0 + (size_t)ii * N_ + (size_t)tile * 16 + s) * DE_ + quad * 8];
                eA[buf][ii][0] = *(const float4*)ep;
                eA[buf][ii][1] = *(const float4*)(ep + 4);
            }
        }
    };
    auto loadB = [&](int buf, int tile) {
        const float* pb = &P1x[(size_t)(b * N_ + tile * 16 + s) * MID_ + quad * 4];
        #pragma unroll
        for (int c = 0; c < 4; ++c) {
            const float4 v = *(const float4*)(pb + c * 16);
            bb[buf][c][0] = v.x; bb[buf][c][1] = v.y;
            bb[buf][c][2] = v.z; bb[buf][c][3] = v.w;
        }
    };

    // ---- Pass A prologue: 2 e-tiles + 2 bias tiles in flight ----
    loadE(0, wv);
    loadE(1, wv + 4);
    loadB(0, wv);
    loadB(1, wv + 4);

    #pragma unroll
    for (int it = 0; it < 16; ++it) {                 // full unroll: static idx
        const int tile = wv + it * 4;
        const int j0   = tile * 16;

        // pack current e -> B fragments
        unsigned af[TI_][4];
        #pragma unroll
        for (int ii = 0; ii < TI_; ++ii) {
            if (quad < 2) {
                af[ii][0] = pk2(eA[it & 1][ii][0].x, eA[it & 1][ii][0].y);
                af[ii][1] = pk2(eA[it & 1][ii][0].z, eA[it & 1][ii][0].w);
                af[ii][2] = pk2(eA[it & 1][ii][1].x, eA[it & 1][ii][1].y);
                af[ii][3] = pk2(eA[it & 1][ii][1].z, eA[it & 1][ii][1].w);
            } else {
                af[ii][0] = af[ii][1] = af[ii][2] = af[ii][3] = 0u;
            }
        }
        // refill this e-buffer for tile it+2
        if (it < 14) loadE(it & 1, tile + 8);
        // prefetch bias two tiles ahead (consumed at it+2, post-MFMA)
        if (it < 14) loadB((it + 2) % 3, tile + 8);

        #pragma unroll
        for (int ii = 0; ii < TI_; ++ii) {
            union { unsigned u[4]; bf16x8 v; } a;
            a.u[0] = af[ii][0]; a.u[1] = af[ii][1];
            a.u[2] = af[ii][2]; a.u[3] = af[ii][3];
            f32x4 acc[4];
            #pragma unroll
            for (int c = 0; c < 4; ++c)
                acc[c] = __builtin_amdgcn_mfma_f32_16x16x32_bf16(bfr[c], a.v, p2l[ii][c], 0, 0, 0);
            // epilogue: leaky-relu + dot(Wa) as a reduction tree (dep ~5)
            float tc[4];
            #pragma unroll
            for (int c = 0; c < 4; ++c) {
                const float w0 = (c == 0 ? wa4[0].x : c == 1 ? wa4[1].x : c == 2 ? wa4[2].x : wa4[3].x);
                const float w1 = (c == 0 ? wa4[0].y : c == 1 ? wa4[1].y : c == 2 ? wa4[2].y : wa4[3].y);
                const float w2 = (c == 0 ? wa4[0].z : c == 1 ? wa4[1].z : c == 2 ? wa4[2].z : wa4[3].z);
                const float w3 = (c == 0 ? wa4[0].w : c == 1 ? wa4[1].w : c == 2 ? wa4[2].w : wa4[3].w);
                float x0 = acc[c][0] + bb[it % 3][c][0];
                float x1 = acc[c][1] + bb[it % 3][c][1];
                float x2 = acc[c][2] + bb[it % 3][c][2];
                float x3 = acc[c][3] + bb[it % 3][c][3];
                x0 = fmaxf(x0, 0.01f * x0);
                x1 = fmaxf(x1, 0.01f * x1);
                x2 = fmaxf(x2, 0.01f * x2);
                x3 = fmaxf(x3, 0.01f * x3);
                tc[c] = (x0 * w0 + x1 * w1) + (x2 * w2 + x3 * w3);
            }
            float part = (tc[0] + tc[1]) + (tc[2] + tc[3]);
            part += __shfl_xor(part, 16);
            part += __shfl_xor(part, 32);
            if (l < 16) lgP[ii][j0 + l] = part;
        }
    }
    __syncthreads();

    // ---- Pass B: masked softmax, wave wv owns row (wv&1), half (wv>>1) ----
    {
        const int rw = wv & 1, h = wv >> 1;
        const int c0 = h * 512 + l * 4;
        const size_t arb = (size_t)(b * N_ + i0 + rw) * N_;
        float4 lv[2], av[2];
        #pragma unroll
        for (int q = 0; q < 2; ++q) {
            lv[q] = *(const float4*)&lgP[rw][c0 + 256 * q];
            av[q] = *(const float4*)&adj[arb + c0 + 256 * q];
        }
        const float NEG = -3.4e38f;
        float m = NEG;
        #pragma unroll
        for (int q = 0; q < 2; ++q) {
            m = fmaxf(m, av[q].x > 0.f ? lv[q].x : NEG);
            m = fmaxf(m, av[q].y > 0.f ? lv[q].y : NEG);
            m = fmaxf(m, av[q].z > 0.f ? lv[q].z : NEG);
            m = fmaxf(m, av[q].w > 0.f ? lv[q].w : NEG);
        }
        #pragma unroll
        for (int o = 1; o < 64; o <<= 1) m = fmaxf(m, __shfl_xor(m, o));
        if (l == 0) pmax[wv] = m;
        __syncthreads();
        m = fmaxf(pmax[rw], pmax[2 + rw]);
        float sum = 0.f;
        #pragma unroll
        for (int q = 0; q < 2; ++q) {
            float4 e4;
            e4.x = av[q].x > 0.f ? __expf(lv[q].x - m) : 0.f;
            e4.y = av[q].y > 0.f ? __expf(lv[q].y - m) : 0.f;
            e4.z = av[q].z > 0.f ? __expf(lv[q].z - m) : 0.f;
            e4.w = av[q].w > 0.f ? __expf(lv[q].w - m) : 0.f;
            *(float4*)&lgP[rw][c0 + 256 * q] = e4;
            sum += (e4.x + e4.y) + (e4.z + e4.w);
        }
        #pragma unroll
        for (int o = 1; o < 64; o <<= 1) sum += __shfl_xor(sum, o);
        if (l == 0) psum[wv] = sum;
        __syncthreads();
        if (t < TI_) sinv[t] = 1.0f / (psum[t] + psum[t + 2]);
        // lgP exp-writes are pre-psum-barrier; sinv read after redv barrier.
    }

    // ---- Pass C: (exp @ values) shared across the 2 i-rows ----
    const int cg = l & 15, jp = l >> 4, ch0 = cg * 8;
    float acc[TI_][8] = {};
    const float* vb = values + (size_t)b * N_ * OUT_ + ch0;
    for (int k = 0; k < 64; ++k) {
        const int j = wv * 4 + jp + k * 16;
        float cw[TI_];
        #pragma unroll
        for (int ii = 0; ii < TI_; ++ii) cw[ii] = lgP[ii][j];
        const float* vp = vb + (size_t)j * OUT_;
        const float4 v0 = *(const float4*)vp;
        const float4 v1 = *(const float4*)(vp + 4);
        const float vv[8] = {v0.x, v0.y, v0.z, v0.w, v1.x, v1.y, v1.z, v1.w};
        #pragma unroll
        for (int ii = 0; ii < TI_; ++ii)
            #pragma unroll
            for (int kk = 0; kk < 8; ++kk)
                acc[ii][kk] += cw[ii] * vv[kk];
    }
    #pragma unroll
    for (int ii = 0; ii < TI_; ++ii)
        #pragma unroll
        for (int kk = 0; kk < 8; ++kk) {
            acc[ii][kk] += __shfl_xor(acc[ii][kk], 16);
            acc[ii][kk] += __shfl_xor(acc[ii][kk], 32);
        }
    if (l < 16) {
        #pragma unroll
        for (int ii = 0; ii < TI_; ++ii)
            #pragma unroll
            for (int q = 0; q < 2; ++q) {
                float4 w4 = make_float4(acc[ii][q * 4], acc[ii][q * 4 + 1],
                                        acc[ii][q * 4 + 2], acc[ii][q * 4 + 3]);
                *(float4*)&redv[wv][l][ii * 8 + q * 4] = w4;
            }
    }
    __syncthreads();
    {
        const int ch = t & 127, g = ch >> 3, kk = ch & 7;
        const int ii = t >> 7;                        // 0..1
        float sum = redv[0][g][ii * 8 + kk];
        #pragma unroll
        for (int w = 1; w < 4; ++w) sum += redv[w][g][ii * 8 + kk];
        const size_t ob = ((size_t)(b * N_ + i0 + ii)) * OUT_ + ch;
        out[ob] = fmaxf(sum * sinv[ii] + skipo[ob], 0.f);
    }
}

extern "C" void kernel_launch(void* const* d_in, const int* in_sizes, int n_in,
                              void* d_out, int out_size, void* d_ws, size_t ws_size,
                              hipStream_t stream) {
    const float* features   = (const float*)d_in[0];
    const float* e_features = (const float*)d_in[1];
    const float* g_features = (const float*)d_in[2];
    const float* adj        = (const float*)d_in[3];
    const float* Wm    = (const float*)d_in[4];
    const float* bm    = (const float*)d_in[5];
    const float* Wskip = (const float*)d_in[6];
    const float* bskip = (const float*)d_in[7];
    const float* W1    = (const float*)d_in[8];
    const float* b1    = (const float*)d_in[9];
    const float* W2    = (const float*)d_in[10];
    const float* b2    = (const float*)d_in[11];
    const float* We    = (const float*)d_in[12];
    const float* be    = (const float*)d_in[13];
    const float* Wg    = (const float*)d_in[14];
    const float* bg    = (const float*)d_in[15];
    const float* Wa    = (const float*)d_in[16];
    float* out = (float*)d_out;

    float* ws      = (float*)d_ws;
    float* values  = ws;                    // 262144 floats
    float* skipo   = ws + 262144;           // 262144
    float* P1x     = ws + 524288;           // 131072 (row-major [node][mid])
    float* p2      = ws + 655360;           // 131072
    float* pg      = ws + 786432;           // 128
    short* We_frag = (short*)(ws + 786560); // 2048 shorts (1024 floats)

    prep_all<<<B_ * N_ / PR_ROWS + 2, 384, 0, stream>>>(
        features, g_features, Wm, bm, Wskip, bskip, W1, b1, W2, b2,
        We, be, Wg, bg, values, skipo, P1x, p2, pg, We_frag);
    gat_main<<<B_ * N_ / TI_, 256, 0, stream>>>(
        e_features, adj, We_frag, Wa, values, skipo, P1x, p2, pg, out);
}

// Round 13
// 274.027 us; speedup vs baseline: 1.0126x; 1.0010x over previous
//
#include <hip/hip_runtime.h>
#include <hip/hip_bf16.h>
#include <cstdint>

#define B_   2
#define N_   1024
#define DN_  128
#define DE_  16
#define DG_  128
#define MID_ 64
#define OUT_ 128
#define TI_  2
#define PR_ROWS 4

typedef short bf16x8 __attribute__((ext_vector_type(8)));
typedef float f32x4  __attribute__((ext_vector_type(4)));

__device__ inline short f2bf(float f) {
    union { float f; unsigned u; } v; v.f = f;
    unsigned r = v.u + 0x7FFFu + ((v.u >> 16) & 1u);   // RTNE
    return (short)(unsigned short)(r >> 16);
}

__device__ inline unsigned pk2(float lo, float hi) {
    union { __hip_bfloat162 h; unsigned u; } p;
    p.h = __float22bfloat162_rn(make_float2(lo, hi));  // v_cvt_pk_bf16_f32
    return p.u;
}

// ---------------------------------------------------------------------------
// Fused prep kernel (R10 version — 8-wide load batching, kept).
// ---------------------------------------------------------------------------
__global__ void __launch_bounds__(384) prep_all(
    const float* __restrict__ features, const float* __restrict__ g_features,
    const float* __restrict__ Wm, const float* __restrict__ bm,
    const float* __restrict__ Wskip, const float* __restrict__ bskip,
    const float* __restrict__ W1, const float* __restrict__ b1,
    const float* __restrict__ W2, const float* __restrict__ b2,
    const float* __restrict__ We, const float* __restrict__ be,
    const float* __restrict__ Wg, const float* __restrict__ bg,
    float* __restrict__ values, float* __restrict__ skipo,
    float* __restrict__ P1x, float* __restrict__ p2,
    float* __restrict__ pg, short* __restrict__ We_frag)
{
    const int t   = threadIdx.x;
    const int blk = blockIdx.x;

    if (blk == 512) {                       // --- We fragment prep ---
        for (int e = t; e < 4 * 64 * 8; e += 384) {
            const int c    = e >> 9;
            const int lane = (e >> 3) & 63;
            const int j    = e & 7;
            const int quad = lane >> 4, s = lane & 15;
            short v = 0;
            if (quad < 2) v = f2bf(We[(quad * 8 + j) * MID_ + c * 16 + s]);
            We_frag[e] = v;
        }
        return;
    }
    if (blk == 513) {                       // --- pg ---
        if (t < MID_) {
            float a0 = bg[t], a1 = bg[t];
            for (int k0 = 0; k0 < DG_; k0 += 8) {
                float w[8];
                #pragma unroll
                for (int u = 0; u < 8; ++u) w[u] = Wg[(k0 + u) * MID_ + t];
                #pragma unroll
                for (int u = 0; u < 8; ++u) {
                    a0 += g_features[k0 + u] * w[u];
                    a1 += g_features[DG_ + k0 + u] * w[u];
                }
            }
            pg[t] = a0; pg[MID_ + t] = a1;
        }
        return;
    }

    // --- per-node projections ---
    const int r0 = blk * PR_ROWS;
    __shared__ float feat[PR_ROWS][DN_];
    for (int idx = t; idx < PR_ROWS * DN_; idx += 384)
        feat[idx >> 7][idx & 127] = features[(size_t)r0 * DN_ + idx];
    __syncthreads();

    const float* W; int c, stride; float base; float* outp; int ostride;
    if (t < 128) {
        W = Wm;    c = t;       stride = OUT_; base = bm[c];
        outp = values + (size_t)r0 * OUT_ + c; ostride = OUT_;
    } else if (t < 256) {
        W = Wskip; c = t - 128; stride = OUT_; base = bskip[c];
        outp = skipo + (size_t)r0 * OUT_ + c;  ostride = OUT_;
    } else if (t < 320) {
        W = W1;    c = t - 256; stride = MID_; base = b1[c] + be[c];
        outp = P1x + (size_t)r0 * MID_ + c;    ostride = MID_;
    } else {
        W = W2;    c = t - 320; stride = MID_; base = b2[c];
        outp = p2 + (size_t)r0 * MID_ + c;     ostride = MID_;
    }

    float acc[PR_ROWS] = {};
    for (int k0 = 0; k0 < DN_; k0 += 8) {
        float w[8];
        #pragma unroll
        for (int u = 0; u < 8; ++u) w[u] = W[(k0 + u) * stride + c];
        #pragma unroll
        for (int u = 0; u < 8; ++u)
            #pragma unroll
            for (int q = 0; q < PR_ROWS; ++q) acc[q] += feat[q][k0 + u] * w[u];
    }
    #pragma unroll
    for (int q = 0; q < PR_ROWS; ++q) outp[q * ostride] = acc[q] + base;
}

// ---------------------------------------------------------------------------
// Main fused kernel (R13): R12 structure + instruction diet.
// R12 post-mortem: VALUBusy 41% x 88us = 36us VALU-execute, but essential
// VALU (pack/epilogue/PassC) is only ~10us -> ~70% is overhead: per-call
// 64-bit address chains in the load lambdas, af->union copies, per-tile
// re-zeroing of quads 2-3 fragments. Diet:
//  - eBase/pBase computed once; per-tile offset is a compile-time constant
//    under the full unroll (one v_add vs a mul chain per load).
//  - persistent zero-initialized A-fragment union: exec-masked pk2 writes
//    only touch quads 0-1; quads 2-3 keep zeros forever (no per-tile movs).
//  - wa as statically-indexed scalars (no ternary chains).
//  - s_setprio(1) around MFMA+epilogue (waves phase-independent here).
// ---------------------------------------------------------------------------
__global__ void __launch_bounds__(256) gat_main(
    const float* __restrict__ e_features, const float* __restrict__ adj,
    const short* __restrict__ We_frag, const float* __restrict__ Wa,
    const float* __restrict__ values, const float* __restrict__ skipo,
    const float* __restrict__ P1x, const float* __restrict__ p2,
    const float* __restrict__ pg, float* __restrict__ out)
{
    const int t    = threadIdx.x;
    const int wv   = t >> 6;                          // 0..3
    const int l    = t & 63;
    const int quad = l >> 4;
    const int s    = l & 15;
    const int r    = blockIdx.x;
    const int b    = (r >> 2) & 1;                    // XCD r%8 -> one batch
    const int i0   = (((r >> 3) << 2) | (r & 3)) * TI_;

    __shared__ float lgP[TI_][N_];
    __shared__ float redv[4][16][20];
    __shared__ float sinv[TI_];
    __shared__ float pmax[4];
    __shared__ float psum[4];

    // ---- block constants ----
    bf16x8 bfr[4];                                    // We A-fragments
    float  wa_s[4][4];                                // Wa, statically indexed
    f32x4  p2l[TI_][4];                               // p2+pg as MFMA C-operand
    #pragma unroll
    for (int c = 0; c < 4; ++c) {
        bfr[c] = *(const bf16x8*)&We_frag[(c * 64 + l) * 8];
        const float4 w4 = *(const float4*)&Wa[c * 16 + quad * 4];
        wa_s[c][0] = w4.x; wa_s[c][1] = w4.y; wa_s[c][2] = w4.z; wa_s[c][3] = w4.w;
        const float4 pg4 = *(const float4*)&pg[b * MID_ + c * 16 + quad * 4];
        #pragma unroll
        for (int ii = 0; ii < TI_; ++ii) {
            const float4 p4 = *(const float4*)&p2[((size_t)(b * N_ + i0 + ii)) * MID_ + c * 16 + quad * 4];
            p2l[ii][c][0] = p4.x + pg4.x;
            p2l[ii][c][1] = p4.y + pg4.y;
            p2l[ii][c][2] = p4.z + pg4.z;
            p2l[ii][c][3] = p4.w + pg4.w;
        }
    }

    // ---- precomputed base pointers (strength reduction) ----
    // e element: ((b*N+i0+ii)*N + tile*16 + s)*DE + quad*8 ; tile=wv+it*4
    const float* eBase = e_features
        + ((size_t)(b * N_ + i0) * N_ + (size_t)(wv * 16 + s)) * DE_ + quad * 8;
    // P1x element: (b*N + tile*16 + s)*MID + quad*4
    const float* pBase = P1x + (size_t)(b * N_ + wv * 16 + s) * MID_ + quad * 4;
    // per-it strides (floats): e: 4 tiles*16 j*DE = 1024 ; ii: N*DE = 16384
    //                          bias: 4 tiles*16 j*MID = 4096

    float4 eA[2][TI_][2];                             // 2-deep e rotation
    float  bb[3][4][4];                               // bias, distance-2 rotation

    // persistent A-fragment unions: quads 2-3 stay zero forever
    union AU { unsigned u[4]; bf16x8 v; };
    AU aU[TI_];
    #pragma unroll
    for (int ii = 0; ii < TI_; ++ii) {
        aU[ii].u[0] = 0u; aU[ii].u[1] = 0u; aU[ii].u[2] = 0u; aU[ii].u[3] = 0u;
    }

    // ---- Pass A prologue: 2 e-tiles + 2 bias tiles in flight ----
    if (quad < 2) {
        #pragma unroll
        for (int ii = 0; ii < TI_; ++ii) {
            eA[0][ii][0] = *(const float4*)(eBase + ii * 16384);
            eA[0][ii][1] = *(const float4*)(eBase + ii * 16384 + 4);
            eA[1][ii][0] = *(const float4*)(eBase + ii * 16384 + 1024);
            eA[1][ii][1] = *(const float4*)(eBase + ii * 16384 + 1024 + 4);
        }
    }
    #pragma unroll
    for (int bt = 0; bt < 2; ++bt)
        #pragma unroll
        for (int c = 0; c < 4; ++c) {
            const float4 v = *(const float4*)(pBase + bt * 4096 + c * 16);
            bb[bt][c][0] = v.x; bb[bt][c][1] = v.y;
            bb[bt][c][2] = v.z; bb[bt][c][3] = v.w;
        }

    #pragma unroll
    for (int it = 0; it < 16; ++it) {                 // full unroll: static idx
        const int j0 = (wv + it * 4) * 16;

        // pack current e -> persistent fragments (exec-masked, quads 0-1)
        if (quad < 2) {
            #pragma unroll
            for (int ii = 0; ii < TI_; ++ii) {
                aU[ii].u[0] = pk2(eA[it & 1][ii][0].x, eA[it & 1][ii][0].y);
                aU[ii].u[1] = pk2(eA[it & 1][ii][0].z, eA[it & 1][ii][0].w);
                aU[ii].u[2] = pk2(eA[it & 1][ii][1].x, eA[it & 1][ii][1].y);
                aU[ii].u[3] = pk2(eA[it & 1][ii][1].z, eA[it & 1][ii][1].w);
            }
        }
        // refill this e-buffer for tile it+2 (constant offsets)
        if (it < 14 && quad < 2) {
            #pragma unroll
            for (int ii = 0; ii < TI_; ++ii) {
                eA[it & 1][ii][0] = *(const float4*)(eBase + ii * 16384 + (it + 2) * 1024);
                eA[it & 1][ii][1] = *(const float4*)(eBase + ii * 16384 + (it + 2) * 1024 + 4);
            }
        }
        // prefetch bias two tiles ahead
        if (it < 14) {
            #pragma unroll
            for (int c = 0; c < 4; ++c) {
                const float4 v = *(const float4*)(pBase + (it + 2) * 4096 + c * 16);
                bb[(it + 2) % 3][c][0] = v.x; bb[(it + 2) % 3][c][1] = v.y;
                bb[(it + 2) % 3][c][2] = v.z; bb[(it + 2) % 3][c][3] = v.w;
            }
        }

        __builtin_amdgcn_s_setprio(1);
        #pragma unroll
        for (int ii = 0; ii < TI_; ++ii) {
            f32x4 acc[4];
            #pragma unroll
            for (int c = 0; c < 4; ++c)
                acc[c] = __builtin_amdgcn_mfma_f32_16x16x32_bf16(bfr[c], aU[ii].v, p2l[ii][c], 0, 0, 0);
            // epilogue: leaky-relu + dot(Wa) as a reduction tree
            float tc[4];
            #pragma unroll
            for (int c = 0; c < 4; ++c) {
                float x0 = acc[c][0] + bb[it % 3][c][0];
                float x1 = acc[c][1] + bb[it % 3][c][1];
                float x2 = acc[c][2] + bb[it % 3][c][2];
                float x3 = acc[c][3] + bb[it % 3][c][3];
                x0 = fmaxf(x0, 0.01f * x0);
                x1 = fmaxf(x1, 0.01f * x1);
                x2 = fmaxf(x2, 0.01f * x2);
                x3 = fmaxf(x3, 0.01f * x3);
                tc[c] = (x0 * wa_s[c][0] + x1 * wa_s[c][1])
                      + (x2 * wa_s[c][2] + x3 * wa_s[c][3]);
            }
            float part = (tc[0] + tc[1]) + (tc[2] + tc[3]);
            part += __shfl_xor(part, 16);
            part += __shfl_xor(part, 32);
            if (l < 16) lgP[ii][j0 + l] = part;
        }
        __builtin_amdgcn_s_setprio(0);
    }
    __syncthreads();

    // ---- Pass B: masked softmax, wave wv owns row (wv&1), half (wv>>1) ----
    {
        const int rw = wv & 1, h = wv >> 1;
        const int c0 = h * 512 + l * 4;
        const size_t arb = (size_t)(b * N_ + i0 + rw) * N_;
        float4 lv[2], av[2];
        #pragma unroll
        for (int q = 0; q < 2; ++q) {
            lv[q] = *(const float4*)&lgP[rw][c0 + 256 * q];
            av[q] = *(const float4*)&adj[arb + c0 + 256 * q];
        }
        const float NEG = -3.4e38f;
        float m = NEG;
        #pragma unroll
        for (int q = 0; q < 2; ++q) {
            m = fmaxf(m, av[q].x > 0.f ? lv[q].x : NEG);
            m = fmaxf(m, av[q].y > 0.f ? lv[q].y : NEG);
            m = fmaxf(m, av[q].z > 0.f ? lv[q].z : NEG);
            m = fmaxf(m, av[q].w > 0.f ? lv[q].w : NEG);
        }
        #pragma unroll
        for (int o = 1; o < 64; o <<= 1) m = fmaxf(m, __shfl_xor(m, o));
        if (l == 0) pmax[wv] = m;
        __syncthreads();
        m = fmaxf(pmax[rw], pmax[2 + rw]);
        float sum = 0.f;
        #pragma unroll
        for (int q = 0; q < 2; ++q) {
            float4 e4;
            e4.x = av[q].x > 0.f ? __expf(lv[q].x - m) : 0.f;
            e4.y = av[q].y > 0.f ? __expf(lv[q].y - m) : 0.f;
            e4.z = av[q].z > 0.f ? __expf(lv[q].z - m) : 0.f;
            e4.w = av[q].w > 0.f ? __expf(lv[q].w - m) : 0.f;
            *(float4*)&lgP[rw][c0 + 256 * q] = e4;
            sum += (e4.x + e4.y) + (e4.z + e4.w);
        }
        #pragma unroll
        for (int o = 1; o < 64; o <<= 1) sum += __shfl_xor(sum, o);
        if (l == 0) psum[wv] = sum;
        __syncthreads();
        if (t < TI_) sinv[t] = 1.0f / (psum[t] + psum[t + 2]);
        // lgP exp-writes are pre-psum-barrier; sinv read after redv barrier.
    }

    // ---- Pass C: (exp @ values) shared across the 2 i-rows ----
    const int cg = l & 15, jp = l >> 4, ch0 = cg * 8;
    float acc[TI_][8] = {};
    const float* vb = values + (size_t)b * N_ * OUT_ + ch0;
    for (int k = 0; k < 64; ++k) {
        const int j = wv * 4 + jp + k * 16;
        float cw[TI_];
        #pragma unroll
        for (int ii = 0; ii < TI_; ++ii) cw[ii] = lgP[ii][j];
        const float* vp = vb + (size_t)j * OUT_;
        const float4 v0 = *(const float4*)vp;
        const float4 v1 = *(const float4*)(vp + 4);
        const float vv[8] = {v0.x, v0.y, v0.z, v0.w, v1.x, v1.y, v1.z, v1.w};
        #pragma unroll
        for (int ii = 0; ii < TI_; ++ii)
            #pragma unroll
            for (int kk = 0; kk < 8; ++kk)
                acc[ii][kk] += cw[ii] * vv[kk];
    }
    #pragma unroll
    for (int ii = 0; ii < TI_; ++ii)
        #pragma unroll
        for (int kk = 0; kk < 8; ++kk) {
            acc[ii][kk] += __shfl_xor(acc[ii][kk], 16);
            acc[ii][kk] += __shfl_xor(acc[ii][kk], 32);
        }
    if (l < 16) {
        #pragma unroll
        for (int ii = 0; ii < TI_; ++ii)
            #pragma unroll
            for (int q = 0; q < 2; ++q) {
                float4 w4 = make_float4(acc[ii][q * 4], acc[ii][q * 4 + 1],
                                        acc[ii][q * 4 + 2], acc[ii][q * 4 + 3]);
                *(float4*)&redv[wv][l][ii * 8 + q * 4] = w4;
            }
    }
    __syncthreads();
    {
        const int ch = t & 127, g = ch >> 3, kk = ch & 7;
        const int ii = t >> 7;                        // 0..1
        float sum = redv[0][g][ii * 8 + kk];
        #pragma unroll
        for (int w = 1; w < 4; ++w) sum += redv[w][g][ii * 8 + kk];
        const size_t ob = ((size_t)(b * N_ + i0 + ii)) * OUT_ + ch;
        out[ob] = fmaxf(sum * sinv[ii] + skipo[ob], 0.f);
    }
}

extern "C" void kernel_launch(void* const* d_in, const int* in_sizes, int n_in,
                              void* d_out, int out_size, void* d_ws, size_t ws_size,
                              hipStream_t stream) {
    const float* features   = (const float*)d_in[0];
    const float* e_features = (const float*)d_in[1];
    const float* g_features = (const float*)d_in[2];
    const float* adj        = (const float*)d_in[3];
    const float* Wm    = (const float*)d_in[4];
    const float* bm    = (const float*)d_in[5];
    const float* Wskip = (const float*)d_in[6];
    const float* bskip = (const float*)d_in[7];
    const float* W1    = (const float*)d_in[8];
    const float* b1    = (const float*)d_in[9];
    const float* W2    = (const float*)d_in[10];
    const float* b2    = (const float*)d_in[11];
    const float* We    = (const float*)d_in[12];
    const float* be    = (const float*)d_in[13];
    const float* Wg    = (const float*)d_in[14];
    const float* bg    = (const float*)d_in[15];
    const float* Wa    = (const float*)d_in[16];
    float* out = (float*)d_out;

    float* ws      = (float*)d_ws;
    float* values  = ws;                    // 262144 floats
    float* skipo   = ws + 262144;           // 262144
    float* P1x     = ws + 524288;           // 131072 (row-major [node][mid])
    float* p2      = ws + 655360;           // 131072
    float* pg      = ws + 786432;           // 128
    short* We_frag = (short*)(ws + 786560); // 2048 shorts (1024 floats)

    prep_all<<<B_ * N_ / PR_ROWS + 2, 384, 0, stream>>>(
        features, g_features, Wm, bm, Wskip, bskip, W1, b1, W2, b2,
        We, be, Wg, bg, values, skipo, P1x, p2, pg, We_frag);
    gat_main<<<B_ * N_ / TI_, 256, 0, stream>>>(
        e_features, adj, We_frag, Wa, values, skipo, P1x, p2, pg, out);
}